// Round 3
// baseline (1886.667 us; speedup 1.0000x reference)
//
#include <hip/hip_runtime.h>

#define B_ROWS 32768
#define D_NETS 16
#define MW     1048576   // 1024*1024

typedef __attribute__((ext_vector_type(8)))  short bf16x8;
typedef __attribute__((ext_vector_type(16))) float f32x16;

__device__ __forceinline__ ushort bf16_rne(float f) {
    unsigned u = __float_as_uint(f);
    unsigned r = u + 0x7FFFu + ((u >> 16) & 1u);
    return (ushort)(r >> 16);
}
__device__ __forceinline__ float bf16_to_f(ushort h) {
    return __uint_as_float(((unsigned)h) << 16);
}

// ---------------------------------------------------------------------------
// prep: split gW2/gW3/gW4 (1024x1024) and gW1 (1024x16) into bf16 hi/lo in ws.
// ws layout (ushort units): W2h@0, W2l@1M, W3h@2M, W3l@3M, W4h@4M, W4l@5M,
//                           W1h@6M, W1l@6M+16384
// ---------------------------------------------------------------------------
__global__ void split_weights(const float* __restrict__ gW1,
                              const float* __restrict__ gW2,
                              const float* __restrict__ gW3,
                              const float* __restrict__ gW4,
                              ushort* __restrict__ ws) {
    int i = blockIdx.x * 256 + threadIdx.x;
    float w; int hoff, loff, idx;
    if (i < MW)            { idx = i;          w = gW2[idx]; hoff = 0;      loff = MW;     }
    else if (i < 2 * MW)   { idx = i - MW;     w = gW3[idx]; hoff = 2 * MW; loff = 3 * MW; }
    else if (i < 3 * MW)   { idx = i - 2 * MW; w = gW4[idx]; hoff = 4 * MW; loff = 5 * MW; }
    else                   { idx = i - 3 * MW; if (idx >= 16384) return;
                             w = gW1[idx]; hoff = 6 * MW; loff = 6 * MW + 16384; }
    ushort h = bf16_rne(w);
    ws[hoff + idx] = h;
    ws[loff + idx] = bf16_rne(w - bf16_to_f(h));
}

// ---------------------------------------------------------------------------
// h-network: unchanged (small share of runtime).
// ---------------------------------------------------------------------------
__global__ __launch_bounds__(256, 1) void h_net_kernel(
    const float* __restrict__ x,
    const float* __restrict__ hW1, const float* __restrict__ hb1,
    const float* __restrict__ hW2, const float* __restrict__ hb2,
    const float* __restrict__ hW3, const float* __restrict__ hb3,
    const float* __restrict__ hW4, const float* __restrict__ hb4,
    const float* __restrict__ hW5, const float* __restrict__ hb5,
    float* __restrict__ out)
{
    __shared__ float s_w[3 * 4096];
    __shared__ float s_w1[64];
    __shared__ float s_b1[64];
    __shared__ float s_bs[3 * 64];
    __shared__ float s_w5[64];
    __shared__ float s_b5;

    const int d = blockIdx.y;
    const int t = threadIdx.x;

    for (int i = t; i < 4096; i += 256) {
        s_w[i]        = hW2[d * 4096 + i];
        s_w[4096 + i] = hW3[d * 4096 + i];
        s_w[8192 + i] = hW4[d * 4096 + i];
    }
    if (t < 64) {
        s_w1[t]       = hW1[d * 64 + t];
        s_b1[t]       = hb1[d * 64 + t];
        s_bs[t]       = hb2[d * 64 + t];
        s_bs[64 + t]  = hb3[d * 64 + t];
        s_bs[128 + t] = hb4[d * 64 + t];
        s_w5[t]       = hW5[d * 64 + t];
        if (t == 0) s_b5 = hb5[d];
    }
    __syncthreads();

    const int row = blockIdx.x * 256 + t;
    const float sv = x[row * 32 + 16 + d];

    float ha[64];
    #pragma unroll
    for (int j = 0; j < 64; ++j)
        ha[j] = fmaxf(fmaf(sv, s_w1[j], s_b1[j]), 0.0f);

    #pragma unroll 1
    for (int L = 0; L < 3; ++L) {
        const float* W  = &s_w[L * 4096];
        const float* bb = &s_bs[L * 64];
        float hn[64];
        #pragma unroll
        for (int g = 0; g < 64; ++g) {
            float a0 = bb[g], a1 = 0.f, a2 = 0.f, a3 = 0.f;
            #pragma unroll
            for (int h4 = 0; h4 < 16; ++h4) {
                float4 wv = *reinterpret_cast<const float4*>(&W[g * 64 + h4 * 4]);
                a0 = fmaf(ha[h4 * 4 + 0], wv.x, a0);
                a1 = fmaf(ha[h4 * 4 + 1], wv.y, a1);
                a2 = fmaf(ha[h4 * 4 + 2], wv.z, a2);
                a3 = fmaf(ha[h4 * 4 + 3], wv.w, a3);
            }
            hn[g] = fmaxf((a0 + a1) + (a2 + a3), 0.0f);
        }
        #pragma unroll
        for (int j = 0; j < 64; ++j) ha[j] = hn[j];
    }

    float o0 = 0.f, o1 = 0.f, o2 = 0.f, o3 = 0.f;
    #pragma unroll
    for (int h4 = 0; h4 < 16; ++h4) {
        o0 = fmaf(ha[h4 * 4 + 0], s_w5[h4 * 4 + 0], o0);
        o1 = fmaf(ha[h4 * 4 + 1], s_w5[h4 * 4 + 1], o1);
        o2 = fmaf(ha[h4 * 4 + 2], s_w5[h4 * 4 + 2], o2);
        o3 = fmaf(ha[h4 * 4 + 3], s_w5[h4 * 4 + 3], o3);
    }
    out[row * D_NETS + d] = (o0 + o1) + (o2 + o3) + s_b5;
}

// ---------------------------------------------------------------------------
// g-network via split-bf16 MFMA (32x32x16), fully fused.
// grid B/32 = 1024 blocks; 1024 threads = 16 waves (4/SIMD); wave w owns cols
// [w*64, w*64+64). Acts (32 x 1024) in LDS as bf16 hi/lo with full-width XOR
// swizzle (ushort col ^= (row&31)<<3 -> conflict-free b128 A reads).
// Whole layer accumulated in regs (32 f32/thread). W frags stream from global
// (L2/L3-resident), software-pipelined 4-deep; A-frags (LDS) 2-deep.
// ---------------------------------------------------------------------------
__global__ __launch_bounds__(1024, 4) void g_net_mfma(
    const float* __restrict__ x,
    const ushort* __restrict__ ws,
    const float* __restrict__ gb1, const float* __restrict__ gb2,
    const float* __restrict__ gb3, const float* __restrict__ gb4,
    const float* __restrict__ gW5, const float* __restrict__ gb5,
    float* __restrict__ out)
{
    __shared__ ushort s_Ah[32 * 1024];   // 64 KiB
    __shared__ ushort s_Al[32 * 1024];   // 64 KiB
    __shared__ ushort s_xh[32 * 16];
    __shared__ ushort s_xl[32 * 16];
    __shared__ float  s_red[1024];

    const int t    = threadIdx.x;
    const int l    = t & 63;
    const int wv   = t >> 6;        // wave 0..15
    const int row0 = blockIdx.x * 32;
    const int n0   = wv * 64;       // wave's 64-col slice
    const int lr   = l & 31;
    const int lk   = l >> 5;
    const int lk8  = lk * 8;
    const int akey = lr << 3;       // full-width swizzle key (ushort units)

    // ---- stage split x[:, :16] ----
    if (t < 512) {
        const int r = t >> 4, c = t & 15;
        float v = x[(row0 + r) * 32 + c];
        ushort h = bf16_rne(v);
        s_xh[r * 16 + c] = h;
        s_xl[r * 16 + c] = bf16_rne(v - bf16_to_f(h));
    }
    __syncthreads();

    f32x16 acc[2];

    // ---- layer 1 (K = 16, one k-step) ----
    {
        const ushort* W1h = ws + 6 * MW;
        const ushort* W1l = W1h + 16384;
        bf16x8 ah = *(const bf16x8*)&s_xh[lr * 16 + lk8];
        bf16x8 al = *(const bf16x8*)&s_xl[lr * 16 + lk8];
        #pragma unroll
        for (int nt = 0; nt < 2; ++nt) {
            const int n = n0 + nt * 32 + lr;
            bf16x8 bh = *(const bf16x8*)&W1h[n * 16 + lk8];
            bf16x8 bl = *(const bf16x8*)&W1l[n * 16 + lk8];
            const float bv = gb1[n];
            f32x16 a;
            #pragma unroll
            for (int r = 0; r < 16; ++r) a[r] = bv;
            a = __builtin_amdgcn_mfma_f32_32x32x16_bf16(ah, bh, a, 0, 0, 0);
            a = __builtin_amdgcn_mfma_f32_32x32x16_bf16(al, bh, a, 0, 0, 0);
            a = __builtin_amdgcn_mfma_f32_32x32x16_bf16(ah, bl, a, 0, 0, 0);
            acc[nt] = a;
        }
        #pragma unroll
        for (int nt = 0; nt < 2; ++nt) {
            const int nc = n0 + nt * 32 + lr;
            #pragma unroll
            for (int r = 0; r < 16; ++r) {
                const int row = (r & 3) + 8 * (r >> 2) + 4 * lk;
                float v2 = fmaxf(acc[nt][r], 0.0f);
                ushort h = bf16_rne(v2);
                const int idx = row * 1024 + (nc ^ ((row & 31) << 3));
                s_Ah[idx] = h;
                s_Al[idx] = bf16_rne(v2 - bf16_to_f(h));
            }
        }
    }
    __syncthreads();

    // ---- layers 2..4 ----
    int wo[2];
    #pragma unroll
    for (int nt = 0; nt < 2; ++nt)
        wo[nt] = (n0 + nt * 32 + lr) * 1024 + lk8;
    const int abase = lr * 1024;

#define LOADB(ks, BH, BL)                                               \
    {                                                                   \
        const int _ko = (ks) * 16;                                      \
        _Pragma("unroll")                                               \
        for (int nt = 0; nt < 2; ++nt) {                                \
            BH[nt] = *(const bf16x8*)&Wh[wo[nt] + _ko];                 \
            BL[nt] = *(const bf16x8*)&Wl[wo[nt] + _ko];                 \
        }                                                               \
    }

#define LOADA(ks, AH, AL)                                               \
    {                                                                   \
        const int _ai = abase + (((ks) * 16 + lk8) ^ akey);             \
        AH = *(const bf16x8*)&s_Ah[_ai];                                \
        AL = *(const bf16x8*)&s_Al[_ai];                                \
    }

#define DOMFMA(AH, AL, BH, BL)                                          \
    {                                                                   \
        _Pragma("unroll")                                               \
        for (int nt = 0; nt < 2; ++nt) {                                \
            acc[nt] = __builtin_amdgcn_mfma_f32_32x32x16_bf16(AH, BH[nt], acc[nt], 0, 0, 0); \
            acc[nt] = __builtin_amdgcn_mfma_f32_32x32x16_bf16(AL, BH[nt], acc[nt], 0, 0, 0); \
            acc[nt] = __builtin_amdgcn_mfma_f32_32x32x16_bf16(AH, BL[nt], acc[nt], 0, 0, 0); \
        }                                                               \
    }

    #pragma unroll 1
    for (int L = 0; L < 3; ++L) {
        const ushort* Wh = ws + (2 * L) * MW;
        const ushort* Wl = ws + (2 * L + 1) * MW;
        const float* gbL = (L == 0) ? gb2 : ((L == 1) ? gb3 : gb4);

        #pragma unroll
        for (int nt = 0; nt < 2; ++nt) {
            const float bv = gbL[n0 + nt * 32 + lr];
            #pragma unroll
            for (int r = 0; r < 16; ++r) acc[nt][r] = bv;
        }

        bf16x8 Bh0[2], Bl0[2], Bh1[2], Bl1[2], Bh2[2], Bl2[2], Bh3[2], Bl3[2];
        bf16x8 Ah0, Al0, Ah1, Al1, Ah2, Al2, Ah3, Al3;

        LOADB(0, Bh0, Bl0);
        LOADB(1, Bh1, Bl1);
        LOADB(2, Bh2, Bl2);
        LOADA(0, Ah0, Al0);
        LOADA(1, Ah1, Al1);

        #pragma unroll 1
        for (int ks = 0; ks < 64; ks += 4) {
            int s3 = ks + 3; s3 = s3 > 63 ? 63 : s3;
            int s4 = ks + 4; s4 = s4 > 63 ? 63 : s4;
            int s5 = ks + 5; s5 = s5 > 63 ? 63 : s5;
            int s6 = ks + 6; s6 = s6 > 63 ? 63 : s6;
            int s2 = ks + 2; s2 = s2 > 63 ? 63 : s2;

            LOADB(s3, Bh3, Bl3);  LOADA(s2, Ah2, Al2);
            DOMFMA(Ah0, Al0, Bh0, Bl0);
            LOADB(s4, Bh0, Bl0);  LOADA(s3, Ah3, Al3);
            DOMFMA(Ah1, Al1, Bh1, Bl1);
            LOADB(s5, Bh1, Bl1);  LOADA(s4, Ah0, Al0);
            DOMFMA(Ah2, Al2, Bh2, Bl2);
            LOADB(s6, Bh2, Bl2);  LOADA(s5, Ah1, Al1);
            DOMFMA(Ah3, Al3, Bh3, Bl3);
        }

        __syncthreads();   // everyone done READING s_Ah/s_Al
        #pragma unroll
        for (int nt = 0; nt < 2; ++nt) {
            const int nc = n0 + nt * 32 + lr;
            #pragma unroll
            for (int r = 0; r < 16; ++r) {
                const int row = (r & 3) + 8 * (r >> 2) + 4 * lk;
                float v2 = fmaxf(acc[nt][r], 0.0f);
                ushort h = bf16_rne(v2);
                const int idx = row * 1024 + (nc ^ ((row & 31) << 3));
                s_Ah[idx] = h;
                s_Al[idx] = bf16_rne(v2 - bf16_to_f(h));
            }
        }
        __syncthreads();   // acts ready for next layer
    }
#undef LOADB
#undef LOADA
#undef DOMFMA

    // ---- layer 5: out_g[row] = act . gW5 + gb5 ----
    {
        const int r = t >> 5;     // 0..31 row
        const int c = t & 31;     // 0..31, 32 k each
        const int rkey = (r & 31) << 3;
        float s = 0.0f;
        #pragma unroll 8
        for (int q = 0; q < 32; ++q) {
            const int k = c * 32 + q;
            const int idx = r * 1024 + (k ^ rkey);
            float a = bf16_to_f(s_Ah[idx]) + bf16_to_f(s_Al[idx]);
            s = fmaf(a, gW5[k], s);
        }
        s_red[t] = s;
    }
    __syncthreads();
    if (t < 32) {
        float sum = gb5[0];
        #pragma unroll
        for (int c = 0; c < 32; ++c) sum += s_red[t * 32 + c];
        out[B_ROWS * D_NETS + row0 + t] = sum;
    }
}

extern "C" void kernel_launch(void* const* d_in, const int* in_sizes, int n_in,
                              void* d_out, int out_size, void* d_ws, size_t ws_size,
                              hipStream_t stream) {
    (void)in_sizes; (void)n_in; (void)out_size; (void)ws_size;

    const float* x   = (const float*)d_in[0];
    const float* hW1 = (const float*)d_in[1];
    const float* hb1 = (const float*)d_in[2];
    const float* hW2 = (const float*)d_in[3];
    const float* hb2 = (const float*)d_in[4];
    const float* hW3 = (const float*)d_in[5];
    const float* hb3 = (const float*)d_in[6];
    const float* hW4 = (const float*)d_in[7];
    const float* hb4 = (const float*)d_in[8];
    const float* hW5 = (const float*)d_in[9];
    const float* hb5 = (const float*)d_in[10];
    const float* gW1 = (const float*)d_in[11];
    const float* gb1 = (const float*)d_in[12];
    const float* gW2 = (const float*)d_in[13];
    const float* gb2 = (const float*)d_in[14];
    const float* gW3 = (const float*)d_in[15];
    const float* gb3 = (const float*)d_in[16];
    const float* gW4 = (const float*)d_in[17];
    const float* gb4 = (const float*)d_in[18];
    const float* gW5 = (const float*)d_in[19];
    const float* gb5 = (const float*)d_in[20];
    float* out = (float*)d_out;
    ushort* wsp = (ushort*)d_ws;

    split_weights<<<(3 * MW + 16384 + 255) / 256, 256, 0, stream>>>(gW1, gW2, gW3, gW4, wsp);

    dim3 gh(B_ROWS / 256, D_NETS);
    h_net_kernel<<<gh, 256, 0, stream>>>(x, hW1, hb1, hW2, hb2, hW3, hb3,
                                         hW4, hb4, hW5, hb5, out);

    g_net_mfma<<<B_ROWS / 32, 1024, 0, stream>>>(x, wsp, gb1, gb2, gb3, gb4,
                                                 gW5, gb5, out);
}

// Round 4
// 1043.612 us; speedup vs baseline: 1.8078x; 1.8078x over previous
//
#include <hip/hip_runtime.h>

#define B_ROWS 32768
#define D_NETS 16
#define MW     1048576   // 1024*1024
#define PKL    131072    // pack-chunks (8 elem) per 1024x1024 layer

typedef __attribute__((ext_vector_type(8)))  short bf16x8;
typedef __attribute__((ext_vector_type(16))) float f32x16;

__device__ __forceinline__ ushort bf16_rne(float f) {
    unsigned u = __float_as_uint(f);
    unsigned r = u + 0x7FFFu + ((u >> 16) & 1u);
    return (ushort)(r >> 16);
}
__device__ __forceinline__ float bf16_to_f(ushort h) {
    return __uint_as_float(((unsigned)h) << 16);
}

// ---------------------------------------------------------------------------
// prep: split gW2/gW3/gW4 into bf16 hi/lo, packed in MFMA-fragment-linear
// order: Wpack[((ks*32+g)*64 + lane)*8 + kk] with lane = khalf*32 + (n&31),
// n = g*32+(n&31), k = ks*16 + khalf*8 + kk. A wave's B-frag load becomes
// base + lane*16B -> one coalesced 1024B transaction.
// ws layout (ushort): W2h@0, W2l@1M, W3h@2M, W3l@3M, W4h@4M, W4l@5M,
//                     W1h@6M (row-major [n][16]), W1l@6M+16384
// ---------------------------------------------------------------------------
__global__ void pack_weights(const float* __restrict__ gW1,
                             const float* __restrict__ gW2,
                             const float* __restrict__ gW3,
                             const float* __restrict__ gW4,
                             ushort* __restrict__ ws) {
    const int p = blockIdx.x * 256 + threadIdx.x;   // one 8-element pack chunk
    if (p < 3 * PKL) {
        const int lz = p / PKL;
        const int pl = p - lz * PKL;
        const float* W = (lz == 0) ? gW2 : ((lz == 1) ? gW3 : gW4);
        const int l  = pl & 63;
        const int g  = (pl >> 6) & 31;
        const int ks = pl >> 11;
        const int n  = g * 32 + (l & 31);
        const int k0 = ks * 16 + (l >> 5) * 8;
        const float* src = &W[n * 1024 + k0];
        ushort* dh = &ws[(size_t)lz * 2 * MW + (size_t)pl * 8];
        ushort* dl = dh + MW;
        #pragma unroll
        for (int kk = 0; kk < 8; ++kk) {
            float w = src[kk];
            ushort h = bf16_rne(w);
            dh[kk] = h;
            dl[kk] = bf16_rne(w - bf16_to_f(h));
        }
    } else {
        const int pl = p - 3 * PKL;
        if (pl >= 2048) return;                      // W1: 16384 elems
        const float* src = &gW1[pl * 8];
        ushort* dh = &ws[6 * MW + pl * 8];
        ushort* dl = dh + 16384;
        #pragma unroll
        for (int kk = 0; kk < 8; ++kk) {
            float w = src[kk];
            ushort h = bf16_rne(w);
            dh[kk] = h;
            dl[kk] = bf16_rne(w - bf16_to_f(h));
        }
    }
}

// ---------------------------------------------------------------------------
// h-network: unchanged (~150 us share).
// ---------------------------------------------------------------------------
__global__ __launch_bounds__(256, 1) void h_net_kernel(
    const float* __restrict__ x,
    const float* __restrict__ hW1, const float* __restrict__ hb1,
    const float* __restrict__ hW2, const float* __restrict__ hb2,
    const float* __restrict__ hW3, const float* __restrict__ hb3,
    const float* __restrict__ hW4, const float* __restrict__ hb4,
    const float* __restrict__ hW5, const float* __restrict__ hb5,
    float* __restrict__ out)
{
    __shared__ float s_w[3 * 4096];
    __shared__ float s_w1[64];
    __shared__ float s_b1[64];
    __shared__ float s_bs[3 * 64];
    __shared__ float s_w5[64];
    __shared__ float s_b5;

    const int d = blockIdx.y;
    const int t = threadIdx.x;

    for (int i = t; i < 4096; i += 256) {
        s_w[i]        = hW2[d * 4096 + i];
        s_w[4096 + i] = hW3[d * 4096 + i];
        s_w[8192 + i] = hW4[d * 4096 + i];
    }
    if (t < 64) {
        s_w1[t]       = hW1[d * 64 + t];
        s_b1[t]       = hb1[d * 64 + t];
        s_bs[t]       = hb2[d * 64 + t];
        s_bs[64 + t]  = hb3[d * 64 + t];
        s_bs[128 + t] = hb4[d * 64 + t];
        s_w5[t]       = hW5[d * 64 + t];
        if (t == 0) s_b5 = hb5[d];
    }
    __syncthreads();

    const int row = blockIdx.x * 256 + t;
    const float sv = x[row * 32 + 16 + d];

    float ha[64];
    #pragma unroll
    for (int j = 0; j < 64; ++j)
        ha[j] = fmaxf(fmaf(sv, s_w1[j], s_b1[j]), 0.0f);

    #pragma unroll 1
    for (int L = 0; L < 3; ++L) {
        const float* W  = &s_w[L * 4096];
        const float* bb = &s_bs[L * 64];
        float hn[64];
        #pragma unroll
        for (int g = 0; g < 64; ++g) {
            float a0 = bb[g], a1 = 0.f, a2 = 0.f, a3 = 0.f;
            #pragma unroll
            for (int h4 = 0; h4 < 16; ++h4) {
                float4 wv = *reinterpret_cast<const float4*>(&W[g * 64 + h4 * 4]);
                a0 = fmaf(ha[h4 * 4 + 0], wv.x, a0);
                a1 = fmaf(ha[h4 * 4 + 1], wv.y, a1);
                a2 = fmaf(ha[h4 * 4 + 2], wv.z, a2);
                a3 = fmaf(ha[h4 * 4 + 3], wv.w, a3);
            }
            hn[g] = fmaxf((a0 + a1) + (a2 + a3), 0.0f);
        }
        #pragma unroll
        for (int j = 0; j < 64; ++j) ha[j] = hn[j];
    }

    float o0 = 0.f, o1 = 0.f, o2 = 0.f, o3 = 0.f;
    #pragma unroll
    for (int h4 = 0; h4 < 16; ++h4) {
        o0 = fmaf(ha[h4 * 4 + 0], s_w5[h4 * 4 + 0], o0);
        o1 = fmaf(ha[h4 * 4 + 1], s_w5[h4 * 4 + 1], o1);
        o2 = fmaf(ha[h4 * 4 + 2], s_w5[h4 * 4 + 2], o2);
        o3 = fmaf(ha[h4 * 4 + 3], s_w5[h4 * 4 + 3], o3);
    }
    out[row * D_NETS + d] = (o0 + o1) + (o2 + o3) + s_b5;
}

// ---------------------------------------------------------------------------
// g-network via split-bf16 MFMA (32x32x16), fully fused.
// grid B/32 = 1024 blocks; 1024 threads = 16 waves; wave wv owns cols
// [wv*64, wv*64+64). Acts (32 x 1024) in LDS bf16 hi/lo, XOR-swizzled.
// W frags stream from global in fragment-linear packed layout (coalesced),
// software-pipelined 4-deep; A-frags (LDS) 2-deep.
// ---------------------------------------------------------------------------
__global__ __launch_bounds__(1024, 4) void g_net_mfma(
    const float* __restrict__ x,
    const ushort* __restrict__ ws,
    const float* __restrict__ gb1, const float* __restrict__ gb2,
    const float* __restrict__ gb3, const float* __restrict__ gb4,
    const float* __restrict__ gW5, const float* __restrict__ gb5,
    float* __restrict__ out)
{
    __shared__ ushort s_Ah[32 * 1024];   // 64 KiB
    __shared__ ushort s_Al[32 * 1024];   // 64 KiB
    __shared__ ushort s_xh[32 * 16];
    __shared__ ushort s_xl[32 * 16];
    __shared__ float  s_red[1024];

    const int t    = threadIdx.x;
    const int l    = t & 63;
    const int wv   = t >> 6;        // wave 0..15
    const int row0 = blockIdx.x * 32;
    const int n0   = wv * 64;       // wave's 64-col slice
    const int lr   = l & 31;
    const int lk   = l >> 5;
    const int lk8  = lk * 8;
    const int akey = lr << 3;       // act swizzle key (ushort units)

    // packed-W per-lane bases for the wave's two 32-col groups
    const int wbase0 = ((wv * 2 + 0) * 64 + l) * 8;
    const int wbase1 = ((wv * 2 + 1) * 64 + l) * 8;

    // ---- stage split x[:, :16] ----
    if (t < 512) {
        const int r = t >> 4, c = t & 15;
        float v = x[(row0 + r) * 32 + c];
        ushort h = bf16_rne(v);
        s_xh[r * 16 + c] = h;
        s_xl[r * 16 + c] = bf16_rne(v - bf16_to_f(h));
    }
    __syncthreads();

    f32x16 acc[2];

    // ---- layer 1 (K = 16, one k-step; W1 row-major [n][16]) ----
    {
        const ushort* W1h = ws + 6 * MW;
        const ushort* W1l = W1h + 16384;
        bf16x8 ah = *(const bf16x8*)&s_xh[lr * 16 + lk8];
        bf16x8 al = *(const bf16x8*)&s_xl[lr * 16 + lk8];
        #pragma unroll
        for (int nt = 0; nt < 2; ++nt) {
            const int n = n0 + nt * 32 + lr;
            bf16x8 bh = *(const bf16x8*)&W1h[n * 16 + lk8];
            bf16x8 bl = *(const bf16x8*)&W1l[n * 16 + lk8];
            const float bv = gb1[n];
            f32x16 a;
            #pragma unroll
            for (int r = 0; r < 16; ++r) a[r] = bv;
            a = __builtin_amdgcn_mfma_f32_32x32x16_bf16(ah, bh, a, 0, 0, 0);
            a = __builtin_amdgcn_mfma_f32_32x32x16_bf16(al, bh, a, 0, 0, 0);
            a = __builtin_amdgcn_mfma_f32_32x32x16_bf16(ah, bl, a, 0, 0, 0);
            acc[nt] = a;
        }
        #pragma unroll
        for (int nt = 0; nt < 2; ++nt) {
            const int nc = n0 + nt * 32 + lr;
            #pragma unroll
            for (int r = 0; r < 16; ++r) {
                const int row = (r & 3) + 8 * (r >> 2) + 4 * lk;
                float v2 = fmaxf(acc[nt][r], 0.0f);
                ushort h = bf16_rne(v2);
                const int idx = row * 1024 + (nc ^ ((row & 31) << 3));
                s_Ah[idx] = h;
                s_Al[idx] = bf16_rne(v2 - bf16_to_f(h));
            }
        }
    }
    __syncthreads();

    // ---- layers 2..4 ----
    const int abase = lr * 1024;

#define LOADB(ks, BH, BL)                                               \
    {                                                                   \
        const int _o = (ks) * 16384;                                    \
        BH[0] = *(const bf16x8*)&Wh[_o + wbase0];                       \
        BL[0] = *(const bf16x8*)&Wl[_o + wbase0];                       \
        BH[1] = *(const bf16x8*)&Wh[_o + wbase1];                       \
        BL[1] = *(const bf16x8*)&Wl[_o + wbase1];                       \
    }

#define LOADA(ks, AH, AL)                                               \
    {                                                                   \
        const int _ai = abase + (((ks) * 16 + lk8) ^ akey);             \
        AH = *(const bf16x8*)&s_Ah[_ai];                                \
        AL = *(const bf16x8*)&s_Al[_ai];                                \
    }

#define DOMFMA(AH, AL, BH, BL)                                          \
    {                                                                   \
        _Pragma("unroll")                                               \
        for (int nt = 0; nt < 2; ++nt) {                                \
            acc[nt] = __builtin_amdgcn_mfma_f32_32x32x16_bf16(AH, BH[nt], acc[nt], 0, 0, 0); \
            acc[nt] = __builtin_amdgcn_mfma_f32_32x32x16_bf16(AL, BH[nt], acc[nt], 0, 0, 0); \
            acc[nt] = __builtin_amdgcn_mfma_f32_32x32x16_bf16(AH, BL[nt], acc[nt], 0, 0, 0); \
        }                                                               \
    }

    #pragma unroll 1
    for (int L = 0; L < 3; ++L) {
        const ushort* Wh = ws + (size_t)(2 * L) * MW;
        const ushort* Wl = ws + (size_t)(2 * L + 1) * MW;
        const float* gbL = (L == 0) ? gb2 : ((L == 1) ? gb3 : gb4);

        #pragma unroll
        for (int nt = 0; nt < 2; ++nt) {
            const float bv = gbL[n0 + nt * 32 + lr];
            #pragma unroll
            for (int r = 0; r < 16; ++r) acc[nt][r] = bv;
        }

        bf16x8 Bh0[2], Bl0[2], Bh1[2], Bl1[2], Bh2[2], Bl2[2], Bh3[2], Bl3[2];
        bf16x8 Ah0, Al0, Ah1, Al1, Ah2, Al2, Ah3, Al3;

        LOADB(0, Bh0, Bl0);
        LOADB(1, Bh1, Bl1);
        LOADB(2, Bh2, Bl2);
        LOADA(0, Ah0, Al0);
        LOADA(1, Ah1, Al1);

        #pragma unroll 1
        for (int ks = 0; ks < 64; ks += 4) {
            int s2 = ks + 2; s2 = s2 > 63 ? 63 : s2;
            int s3 = ks + 3; s3 = s3 > 63 ? 63 : s3;
            int s4 = ks + 4; s4 = s4 > 63 ? 63 : s4;
            int s5 = ks + 5; s5 = s5 > 63 ? 63 : s5;
            int s6 = ks + 6; s6 = s6 > 63 ? 63 : s6;

            LOADB(s3, Bh3, Bl3);  LOADA(s2, Ah2, Al2);
            DOMFMA(Ah0, Al0, Bh0, Bl0);
            LOADB(s4, Bh0, Bl0);  LOADA(s3, Ah3, Al3);
            DOMFMA(Ah1, Al1, Bh1, Bl1);
            LOADB(s5, Bh1, Bl1);  LOADA(s4, Ah0, Al0);
            DOMFMA(Ah2, Al2, Bh2, Bl2);
            LOADB(s6, Bh2, Bl2);  LOADA(s5, Ah1, Al1);
            DOMFMA(Ah3, Al3, Bh3, Bl3);
        }

        __syncthreads();   // everyone done READING s_Ah/s_Al
        #pragma unroll
        for (int nt = 0; nt < 2; ++nt) {
            const int nc = n0 + nt * 32 + lr;
            #pragma unroll
            for (int r = 0; r < 16; ++r) {
                const int row = (r & 3) + 8 * (r >> 2) + 4 * lk;
                float v2 = fmaxf(acc[nt][r], 0.0f);
                ushort h = bf16_rne(v2);
                const int idx = row * 1024 + (nc ^ ((row & 31) << 3));
                s_Ah[idx] = h;
                s_Al[idx] = bf16_rne(v2 - bf16_to_f(h));
            }
        }
        __syncthreads();   // acts ready for next layer
    }
#undef LOADB
#undef LOADA
#undef DOMFMA

    // ---- layer 5: out_g[row] = act . gW5 + gb5 ----
    {
        const int r = t >> 5;     // 0..31 row
        const int c = t & 31;     // 0..31, 32 k each
        const int rkey = (r & 31) << 3;
        float s = 0.0f;
        #pragma unroll 8
        for (int q = 0; q < 32; ++q) {
            const int k = c * 32 + q;
            const int idx = r * 1024 + (k ^ rkey);
            float a = bf16_to_f(s_Ah[idx]) + bf16_to_f(s_Al[idx]);
            s = fmaf(a, gW5[k], s);
        }
        s_red[t] = s;
    }
    __syncthreads();
    if (t < 32) {
        float sum = gb5[0];
        #pragma unroll
        for (int c = 0; c < 32; ++c) sum += s_red[t * 32 + c];
        out[B_ROWS * D_NETS + row0 + t] = sum;
    }
}

extern "C" void kernel_launch(void* const* d_in, const int* in_sizes, int n_in,
                              void* d_out, int out_size, void* d_ws, size_t ws_size,
                              hipStream_t stream) {
    (void)in_sizes; (void)n_in; (void)out_size; (void)ws_size;

    const float* x   = (const float*)d_in[0];
    const float* hW1 = (const float*)d_in[1];
    const float* hb1 = (const float*)d_in[2];
    const float* hW2 = (const float*)d_in[3];
    const float* hb2 = (const float*)d_in[4];
    const float* hW3 = (const float*)d_in[5];
    const float* hb3 = (const float*)d_in[6];
    const float* hW4 = (const float*)d_in[7];
    const float* hb4 = (const float*)d_in[8];
    const float* hW5 = (const float*)d_in[9];
    const float* hb5 = (const float*)d_in[10];
    const float* gW1 = (const float*)d_in[11];
    const float* gb1 = (const float*)d_in[12];
    const float* gW2 = (const float*)d_in[13];
    const float* gb2 = (const float*)d_in[14];
    const float* gW3 = (const float*)d_in[15];
    const float* gb3 = (const float*)d_in[16];
    const float* gW4 = (const float*)d_in[17];
    const float* gb4 = (const float*)d_in[18];
    const float* gW5 = (const float*)d_in[19];
    const float* gb5 = (const float*)d_in[20];
    float* out = (float*)d_out;
    ushort* wsp = (ushort*)d_ws;

    pack_weights<<<(3 * PKL + 2048 + 255) / 256, 256, 0, stream>>>(gW1, gW2, gW3, gW4, wsp);

    dim3 gh(B_ROWS / 256, D_NETS);
    h_net_kernel<<<gh, 256, 0, stream>>>(x, hW1, hb1, hW2, hb2, hW3, hb3,
                                         hW4, hb4, hW5, hb5, out);

    g_net_mfma<<<B_ROWS / 32, 1024, 0, stream>>>(x, wsp, gb1, gb2, gb3, gb4,
                                                 gW5, gb5, out);
}